// Round 4
// baseline (63382.507 us; speedup 1.0000x reference)
//
#include <hip/hip_runtime.h>
#include <math.h>

#define NTHR 512
#define BT 2

__device__ __forceinline__ float fast_tanh(float x) {
    float ax = fabsf(x);
    float e  = __expf(-2.0f * ax);                       // in (0,1], never overflows
    float r  = (1.0f - e) * __builtin_amdgcn_rcpf(1.0f + e);
    return copysignf(r, x);
}

__global__ __launch_bounds__(NTHR, 4)
void odernn_kernel(const float* __restrict__ quat,   // [1024][64][4]
                   const float* __restrict__ W1,     // [68][256]
                   const float* __restrict__ b1,     // [256]
                   const float* __restrict__ W2,     // [256][256]
                   const float* __restrict__ b2,     // [256]
                   const float* __restrict__ W3,     // [256][64]
                   const float* __restrict__ b3,     // [64]
                   float* __restrict__ out)          // [1024*64] hfinal, then [1024][64][8][64] traj
{
    // LDS: activations + partial sums only; ALL weights live in registers.
    __shared__ __align__(16) float sRed[4096];    // 16 KB, union: L2 partials [8][2][256] / L3 partials [32][2][64]
    __shared__ __align__(16) float sH1[2][256];   // 2 KB
    __shared__ __align__(16) float sH2[2][256];   // 2 KB
    __shared__ __align__(16) float sC1[2][256];   // 2 KB
    __shared__ __align__(16) float sY[2][64];     // 0.5 KB

    const int t = threadIdx.x;
    const int w = t >> 6;            // wave 0..7
    const int l = t & 63;            // lane
    const int b0 = blockIdx.x * BT;

    // ---- phase mappings (all dup-free weight ownership) ----
    // A (L1): lane-pair k-split: col j1a, k-half kha
    const int j1a = t >> 1;          // 0..255
    const int kha = (t & 1) * 32;    // k base: 0 or 32
    // B (L2): wave = k-slice (32 k), lane = j-quad
    const int kb2 = w * 32;
    // C (L2 reduce): col j1c, batch bc
    const int j1c = t & 255;
    const int bc  = t >> 8;          // 0 or 1
    // D (L3): u3 = j-quad, ks3 = k-slice (32 slices of 8)
    const int u3  = t & 15;
    const int ks3 = t >> 4;
    const int kb3 = ks3 * 8;
    // E (RK4, t<128): batch rb, state dim rj
    const int rb = (t >> 6) & 1;
    const int rj = l;

    // ---- weights -> registers (loaded once) ----
    float w1r[32];                                   // W1h[kha+k][j1a]
    #pragma unroll
    for (int k = 0; k < 32; ++k) w1r[k] = W1[(kha + k) * 256 + j1a];

    float w2r[128];                                  // W2[kb2+k][l*4+jj]
    const float4* __restrict__ W2v4 = (const float4*)W2;
    #pragma unroll
    for (int k = 0; k < 32; ++k) {
        float4 v = W2v4[(size_t)(kb2 + k) * 64 + l];
        w2r[k * 4 + 0] = v.x; w2r[k * 4 + 1] = v.y;
        w2r[k * 4 + 2] = v.z; w2r[k * 4 + 3] = v.w;
    }
    float w3r[32];                                   // W3[kb3+k][u3*4+jj]
    #pragma unroll
    for (int k = 0; k < 8; ++k) {
        float4 v = *(const float4*)&W3[(kb3 + k) * 64 + u3 * 4];
        w3r[k * 4 + 0] = v.x; w3r[k * 4 + 1] = v.y;
        w3r[k * 4 + 2] = v.z; w3r[k * 4 + 3] = v.w;
    }
    float w1q[4];                                    // q-part of W1, col j1c (used t<256)
    #pragma unroll
    for (int m = 0; m < 4; ++m) w1q[m] = W1[(64 + m) * 256 + j1c];

    const float rb1  = b1[j1c];
    const float rb2c = b2[j1c];
    const float rb3e = b3[rj];

    float rH  = (rj == 0) ? 1.0f : 0.0f;   // meaningful for t<128
    float rk1 = 0.0f, rk2 = 0.0f, rk3 = 0.0f;
    if (t < 128) sY[rb][rj] = rH;

    const float dt = 1.0f / 7.0f;
    float* __restrict__ traj = out + 1024 * 64;

    for (int s = 0; s < 64; ++s) {
        // ---- per-token: c1 = b1 + q @ W1q ; record initial state ----
        if (t < 256) {
            float4 q0 = *(const float4*)&quat[((size_t)(b0 + 0) * 64 + s) * 4];
            float4 q1 = *(const float4*)&quat[((size_t)(b0 + 1) * 64 + s) * 4];
            sC1[0][t] = fmaf(q0.x, w1q[0], fmaf(q0.y, w1q[1], fmaf(q0.z, w1q[2], fmaf(q0.w, w1q[3], rb1))));
            sC1[1][t] = fmaf(q1.x, w1q[0], fmaf(q1.y, w1q[1], fmaf(q1.z, w1q[2], fmaf(q1.w, w1q[3], rb1))));
        }
        if (t < 128) traj[(((size_t)(b0 + rb) * 64 + s) * 8 + 0) * 64 + rj] = rH;
        __syncthreads();

        for (int step = 1; step < 8; ++step) {
            #pragma unroll
            for (int mode = 1; mode <= 4; ++mode) {
                // ---------- A: h1 = tanh(y @ W1h + c1), k-split across lane pairs ----------
                {
                    float a0 = 0.0f, a1 = 0.0f;
                    const float4* y4 = (const float4*)&sY[0][0];
                    const int yb = (t & 1) * 8;      // float4 index of k-half
                    #pragma unroll
                    for (int k4 = 0; k4 < 8; ++k4) {
                        float4 y0 = y4[0 * 16 + yb + k4];
                        float4 y1 = y4[1 * 16 + yb + k4];
                        #pragma unroll
                        for (int r = 0; r < 4; ++r) {
                            float wv = w1r[k4 * 4 + r];
                            a0 = fmaf(((const float*)&y0)[r], wv, a0);
                            a1 = fmaf(((const float*)&y1)[r], wv, a1);
                        }
                    }
                    // lane-pair reduce (DPP, no LDS, no barrier)
                    a0 += __shfl_xor(a0, 1);
                    a1 += __shfl_xor(a1, 1);
                    // even lanes own batch 0, odd own batch 1
                    const int bw = t & 1;
                    float vA = bw ? a1 : a0;
                    sH1[bw][j1a] = fast_tanh(vA + sC1[bw][j1a]);
                }
                __syncthreads();
                // ---------- B: layer-2 partials, W2 entirely in registers ----------
                {
                    float acc[2][4];
                    #pragma unroll
                    for (int bb = 0; bb < 2; ++bb)
                        #pragma unroll
                        for (int jj = 0; jj < 4; ++jj) acc[bb][jj] = 0.0f;
                    #pragma unroll
                    for (int k4 = 0; k4 < 8; ++k4) {
                        const int k = kb2 + k4 * 4;
                        float4 h0 = *(const float4*)&sH1[0][k];
                        float4 h1v = *(const float4*)&sH1[1][k];
                        #pragma unroll
                        for (int r = 0; r < 4; ++r) {
                            const int wi = (k4 * 4 + r) * 4;
                            float f0 = ((const float*)&h0)[r];
                            float f1 = ((const float*)&h1v)[r];
                            #pragma unroll
                            for (int jj = 0; jj < 4; ++jj) {
                                acc[0][jj] = fmaf(f0, w2r[wi + jj], acc[0][jj]);
                                acc[1][jj] = fmaf(f1, w2r[wi + jj], acc[1][jj]);
                            }
                        }
                    }
                    // partials: sRed as [8 ks][2 b][256 j]
                    #pragma unroll
                    for (int bb = 0; bb < 2; ++bb)
                        *(float4*)&sRed[w * 512 + bb * 256 + l * 4] =
                            make_float4(acc[bb][0], acc[bb][1], acc[bb][2], acc[bb][3]);
                }
                __syncthreads();
                // ---------- C: layer-2 reduce + tanh ----------
                {
                    float v0 = rb2c, v1 = 0.0f;
                    #pragma unroll
                    for (int ks = 0; ks < 8; ks += 2) {
                        v0 += sRed[ks * 512 + bc * 256 + j1c];
                        v1 += sRed[(ks + 1) * 512 + bc * 256 + j1c];
                    }
                    sH2[bc][j1c] = fast_tanh(v0 + v1);
                }
                __syncthreads();
                // ---------- D: layer-3 partials, W3 in registers ----------
                {
                    float acc[2][4];
                    #pragma unroll
                    for (int bb = 0; bb < 2; ++bb)
                        #pragma unroll
                        for (int jj = 0; jj < 4; ++jj) acc[bb][jj] = 0.0f;
                    #pragma unroll
                    for (int k4 = 0; k4 < 2; ++k4) {
                        const int k = kb3 + k4 * 4;
                        float4 h0 = *(const float4*)&sH2[0][k];
                        float4 h1v = *(const float4*)&sH2[1][k];
                        #pragma unroll
                        for (int r = 0; r < 4; ++r) {
                            const int wi = (k4 * 4 + r) * 4;
                            float f0 = ((const float*)&h0)[r];
                            float f1 = ((const float*)&h1v)[r];
                            #pragma unroll
                            for (int jj = 0; jj < 4; ++jj) {
                                acc[0][jj] = fmaf(f0, w3r[wi + jj], acc[0][jj]);
                                acc[1][jj] = fmaf(f1, w3r[wi + jj], acc[1][jj]);
                            }
                        }
                    }
                    // partials: sRed as [32 ks][2 b][64 j]
                    #pragma unroll
                    for (int bb = 0; bb < 2; ++bb)
                        *(float4*)&sRed[ks3 * 128 + bb * 64 + u3 * 4] =
                            make_float4(acc[bb][0], acc[bb][1], acc[bb][2], acc[bb][3]);
                }
                __syncthreads();
                // ---------- E: layer-3 reduce + RK4 (3/8-rule) ----------
                if (t < 128) {
                    float s0 = rb3e, s1 = 0.0f, s2 = 0.0f, s3 = 0.0f;
                    #pragma unroll
                    for (int ks = 0; ks < 32; ks += 4) {
                        s0 += sRed[(ks + 0) * 128 + rb * 64 + rj];
                        s1 += sRed[(ks + 1) * 128 + rb * 64 + rj];
                        s2 += sRed[(ks + 2) * 128 + rb * 64 + rj];
                        s3 += sRed[(ks + 3) * 128 + rb * 64 + rj];
                    }
                    float k = (s0 + s1) + (s2 + s3);
                    float ynew;
                    if (mode == 1) {
                        rk1 = k;
                        ynew = fmaf(dt * (1.0f / 3.0f), rk1, rH);
                    } else if (mode == 2) {
                        rk2 = k;
                        ynew = fmaf(dt, rk2 - rk1 * (1.0f / 3.0f), rH);
                    } else if (mode == 3) {
                        rk3 = k;
                        ynew = fmaf(dt, rk1 - rk2 + rk3, rH);
                    } else {
                        rH = fmaf(dt * 0.125f, rk1 + 3.0f * (rk2 + rk3) + k, rH);
                        ynew = rH;
                        traj[(((size_t)(b0 + rb) * 64 + s) * 8 + step) * 64 + rj] = rH;
                    }
                    sY[rb][rj] = ynew;
                }
                __syncthreads();
            }
        }
    }
    if (t < 128) out[(size_t)(b0 + rb) * 64 + rj] = rH;
}

extern "C" void kernel_launch(void* const* d_in, const int* in_sizes, int n_in,
                              void* d_out, int out_size, void* d_ws, size_t ws_size,
                              hipStream_t stream) {
    const float* quat = (const float*)d_in[0];
    const float* W1   = (const float*)d_in[1];
    const float* b1   = (const float*)d_in[2];
    const float* W2   = (const float*)d_in[3];
    const float* b2   = (const float*)d_in[4];
    const float* W3   = (const float*)d_in[5];
    const float* b3   = (const float*)d_in[6];
    float* out = (float*)d_out;

    odernn_kernel<<<1024 / BT, NTHR, 0, stream>>>(quat, W1, b1, W2, b2, W3, b3, out);
}

// Round 5
// 7789.453 us; speedup vs baseline: 8.1370x; 8.1370x over previous
//
#include <hip/hip_runtime.h>
#include <math.h>

#define NTHR 512
#define BT 4

__device__ __forceinline__ float fast_tanh(float x) {
    float ax = fabsf(x);
    float e  = __expf(-2.0f * ax);                       // in (0,1], never overflows
    float r  = (1.0f - e) * __builtin_amdgcn_rcpf(1.0f + e);
    return copysignf(r, x);
}

__global__ __launch_bounds__(NTHR, 2)
void odernn_kernel(const float* __restrict__ quat,   // [1024][64][4]
                   const float* __restrict__ W1,     // [68][256]
                   const float* __restrict__ b1,     // [256]
                   const float* __restrict__ W2,     // [256][256]
                   const float* __restrict__ b2,     // [256]
                   const float* __restrict__ W3,     // [256][64]
                   const float* __restrict__ b3,     // [64]
                   float* __restrict__ out)          // [1024*64] hfinal, then [1024][64][8][64] traj
{
    // LDS: activations only. No partial-sum buffers (in-wave butterflies), no weights.
    __shared__ __align__(16) float sH1[4][256];   // 4 KB
    __shared__ __align__(16) float sH2[4][256];   // 4 KB
    __shared__ __align__(16) float sC1[4][256];   // 4 KB
    __shared__ __align__(16) float sY[4][64];     // 1 KB

    const int t = threadIdx.x;
    const int w = t >> 6;            // wave 0..7
    const int l = t & 63;            // lane
    const int b0 = blockIdx.x * BT;

    // ---- A (L1): lane-pair k-split: col j1a, k-half via t&1 ----
    const int j1a = t >> 1;          // 0..255
    const int bw  = (t & 1) * 2;     // even lanes own batches {0,1}, odd {2,3}
    const int yb  = (t & 1) * 8;     // float4 offset of k-half
    // ---- B (L2): k-slice in lane bits 0..2 (in-wave reduce), j-quad in (w, lane bits 3..5) ----
    const int ks2 = l & 7;           // 8 k-slices of 32
    const int u2  = (w << 3) | (l >> 3);   // j-quad 0..63
    const int kb2 = ks2 * 32;
    //   B output ownership (after butterfly): batch bB, cols jB0/jB1
    const int bB  = l & 3;
    const int jj0 = (l >> 2) & 1;
    const int jB0 = u2 * 4 + jj0;
    const int jB1 = u2 * 4 + jj0 + 2;
    // ---- D (L3): k-slice in lane bits 0..3 (in-wave reduce), j-pair in (w, lane bits 4..5) ----
    const int ks3  = l & 15;         // 16 k-slices of 16
    const int jp3  = (w << 2) | (l >> 4);  // j-pair 0..31
    const int kb3  = ks3 * 16;
    const int rot3 = (l >> 1) & 3;   // bank-spread rotation (same for l and l^8)
    //   D/E output ownership: batch bD, state dim jD; lanes l and l^8 are redundant twins
    const int bD = (l >> 1) & 3;
    const int jD = jp3 * 2 + (l & 1);
    const bool ownD = (l & 8) == 0;

    // ---- weights -> registers (dup-free; load order pre-rotated so FMA indices stay static) ----
    float w1r[32];                                   // W1h[(t&1)*32 + k][j1a]
    #pragma unroll
    for (int k = 0; k < 32; ++k) w1r[k] = W1[((t & 1) * 32 + k) * 256 + j1a];

    float w2r[128];                                  // W2[kb2 + rot(k)][u2*4 + jj]
    #pragma unroll
    for (int k4 = 0; k4 < 8; ++k4) {
        const int ke = (k4 + ks2) & 7;
        #pragma unroll
        for (int r = 0; r < 4; ++r) {
            float4 v = *(const float4*)&W2[(size_t)(kb2 + ke * 4 + r) * 256 + u2 * 4];
            w2r[(k4 * 4 + r) * 4 + 0] = v.x;
            w2r[(k4 * 4 + r) * 4 + 1] = v.y;
            w2r[(k4 * 4 + r) * 4 + 2] = v.z;
            w2r[(k4 * 4 + r) * 4 + 3] = v.w;
        }
    }
    float w3r[32];                                   // W3[kb3 + rot(k)][jp3*2 + jj]
    #pragma unroll
    for (int k4 = 0; k4 < 4; ++k4) {
        const int ke = (k4 + rot3) & 3;
        #pragma unroll
        for (int r = 0; r < 4; ++r) {
            float2 v = *(const float2*)&W3[(kb3 + ke * 4 + r) * 64 + jp3 * 2];
            w3r[(k4 * 4 + r) * 2 + 0] = v.x;
            w3r[(k4 * 4 + r) * 2 + 1] = v.y;
        }
    }
    const float rb2_0 = b2[jB0];
    const float rb2_1 = b2[jB1];
    const float rb3   = b3[jD];

    float rH  = (jD == 0) ? 1.0f : 0.0f;
    float rk1 = 0.0f, rk2 = 0.0f, rk3 = 0.0f;
    if (ownD) sY[bD][jD] = rH;

    const float dt = 1.0f / 7.0f;
    float* __restrict__ traj = out + 1024 * 64;

    for (int s = 0; s < 64; ++s) {
        // ---- per-token: c1 = b1 + q @ W1q (W1 q-rows + b1 read from global, L2-hot) ----
        if (t < 256) {
            float w1q0 = W1[64 * 256 + t];
            float w1q1 = W1[65 * 256 + t];
            float w1q2 = W1[66 * 256 + t];
            float w1q3 = W1[67 * 256 + t];
            float bb1  = b1[t];
            float4 q0 = *(const float4*)&quat[((size_t)(b0 + 0) * 64 + s) * 4];
            float4 q1 = *(const float4*)&quat[((size_t)(b0 + 1) * 64 + s) * 4];
            float4 q2 = *(const float4*)&quat[((size_t)(b0 + 2) * 64 + s) * 4];
            float4 q3 = *(const float4*)&quat[((size_t)(b0 + 3) * 64 + s) * 4];
            sC1[0][t] = fmaf(q0.x, w1q0, fmaf(q0.y, w1q1, fmaf(q0.z, w1q2, fmaf(q0.w, w1q3, bb1))));
            sC1[1][t] = fmaf(q1.x, w1q0, fmaf(q1.y, w1q1, fmaf(q1.z, w1q2, fmaf(q1.w, w1q3, bb1))));
            sC1[2][t] = fmaf(q2.x, w1q0, fmaf(q2.y, w1q1, fmaf(q2.z, w1q2, fmaf(q2.w, w1q3, bb1))));
            sC1[3][t] = fmaf(q3.x, w1q0, fmaf(q3.y, w1q1, fmaf(q3.z, w1q2, fmaf(q3.w, w1q3, bb1))));
        }
        if (ownD) traj[(((size_t)(b0 + bD) * 64 + s) * 8 + 0) * 64 + jD] = rH;
        __syncthreads();

        for (int step = 1; step < 8; ++step) {
            #pragma unroll
            for (int mode = 1; mode <= 4; ++mode) {
                // ---------- A: h1 = tanh(y @ W1h + c1), lane-pair k-split ----------
                {
                    float a0 = 0.0f, a1 = 0.0f, a2 = 0.0f, a3 = 0.0f;
                    const float4* y4 = (const float4*)&sY[0][0];
                    #pragma unroll
                    for (int k4 = 0; k4 < 8; ++k4) {
                        float4 y0 = y4[0 * 16 + yb + k4];
                        float4 y1 = y4[1 * 16 + yb + k4];
                        float4 y2 = y4[2 * 16 + yb + k4];
                        float4 y3 = y4[3 * 16 + yb + k4];
                        #pragma unroll
                        for (int r = 0; r < 4; ++r) {
                            float wv = w1r[k4 * 4 + r];
                            a0 = fmaf(((const float*)&y0)[r], wv, a0);
                            a1 = fmaf(((const float*)&y1)[r], wv, a1);
                            a2 = fmaf(((const float*)&y2)[r], wv, a2);
                            a3 = fmaf(((const float*)&y3)[r], wv, a3);
                        }
                    }
                    a0 += __shfl_xor(a0, 1);
                    a1 += __shfl_xor(a1, 1);
                    a2 += __shfl_xor(a2, 1);
                    a3 += __shfl_xor(a3, 1);
                    float vA = (t & 1) ? a2 : a0;
                    float vB = (t & 1) ? a3 : a1;
                    sH1[bw][j1a]     = fast_tanh(vA + sC1[bw][j1a]);
                    sH1[bw + 1][j1a] = fast_tanh(vB + sC1[bw + 1][j1a]);
                }
                __syncthreads();
                // ---------- B+C: layer-2, k-reduce in-wave (shfl butterfly), tanh, write sH2 ----------
                {
                    float acc[4][4];
                    #pragma unroll
                    for (int bb = 0; bb < 4; ++bb)
                        #pragma unroll
                        for (int jj = 0; jj < 4; ++jj) acc[bb][jj] = 0.0f;
                    #pragma unroll
                    for (int k4 = 0; k4 < 8; ++k4) {
                        const int ka = kb2 + ((k4 + ks2) & 7) * 4;   // rotated: conflict-free banks
                        #pragma unroll
                        for (int bb = 0; bb < 4; ++bb) {
                            float4 h = *(const float4*)&sH1[bb][ka];
                            #pragma unroll
                            for (int r = 0; r < 4; ++r) {
                                const int wi = (k4 * 4 + r) * 4;
                                float f = ((const float*)&h)[r];
                                acc[bb][0] = fmaf(f, w2r[wi + 0], acc[bb][0]);
                                acc[bb][1] = fmaf(f, w2r[wi + 1], acc[bb][1]);
                                acc[bb][2] = fmaf(f, w2r[wi + 2], acc[bb][2]);
                                acc[bb][3] = fmaf(f, w2r[wi + 3], acc[bb][3]);
                            }
                        }
                    }
                    // butterfly over 8 k-slices (lane bits 0..2); all lanes end with full sums
                    #pragma unroll
                    for (int m = 1; m <= 4; m <<= 1)
                        #pragma unroll
                        for (int bb = 0; bb < 4; ++bb)
                            #pragma unroll
                            for (int jj = 0; jj < 4; ++jj)
                                acc[bb][jj] += __shfl_xor(acc[bb][jj], m);
                    // select this lane's 2 outputs: (bB, jj0) and (bB, jj0+2) - static reg indices
                    float z0 = (l & 4) ? acc[0][1] : acc[0][0];
                    float z1 = (l & 4) ? acc[1][1] : acc[1][0];
                    float z2 = (l & 4) ? acc[2][1] : acc[2][0];
                    float z3 = (l & 4) ? acc[3][1] : acc[3][0];
                    float y0 = (l & 1) ? z1 : z0;
                    float y1 = (l & 1) ? z3 : z2;
                    float o0 = (l & 2) ? y1 : y0;
                    z0 = (l & 4) ? acc[0][3] : acc[0][2];
                    z1 = (l & 4) ? acc[1][3] : acc[1][2];
                    z2 = (l & 4) ? acc[2][3] : acc[2][2];
                    z3 = (l & 4) ? acc[3][3] : acc[3][2];
                    y0 = (l & 1) ? z1 : z0;
                    y1 = (l & 1) ? z3 : z2;
                    float o1 = (l & 2) ? y1 : y0;
                    sH2[bB][jB0] = fast_tanh(o0 + rb2_0);
                    sH2[bB][jB1] = fast_tanh(o1 + rb2_1);
                }
                __syncthreads();
                // ---------- D+E: layer-3 in-wave reduce + RK4 (3/8-rule), no LDS partials ----------
                {
                    float acc[4][2];
                    #pragma unroll
                    for (int bb = 0; bb < 4; ++bb) { acc[bb][0] = 0.0f; acc[bb][1] = 0.0f; }
                    #pragma unroll
                    for (int k4 = 0; k4 < 4; ++k4) {
                        const int ka = kb3 + ((k4 + rot3) & 3) * 4;
                        #pragma unroll
                        for (int bb = 0; bb < 4; ++bb) {
                            float4 h = *(const float4*)&sH2[bb][ka];
                            #pragma unroll
                            for (int r = 0; r < 4; ++r) {
                                const int wi = (k4 * 4 + r) * 2;
                                float f = ((const float*)&h)[r];
                                acc[bb][0] = fmaf(f, w3r[wi + 0], acc[bb][0]);
                                acc[bb][1] = fmaf(f, w3r[wi + 1], acc[bb][1]);
                            }
                        }
                    }
                    // butterfly over 16 k-slices (lane bits 0..3)
                    #pragma unroll
                    for (int m = 1; m <= 8; m <<= 1)
                        #pragma unroll
                        for (int bb = 0; bb < 4; ++bb) {
                            acc[bb][0] += __shfl_xor(acc[bb][0], m);
                            acc[bb][1] += __shfl_xor(acc[bb][1], m);
                        }
                    // select this lane's (bD, jD) sum - static reg indices
                    float z0 = (l & 1) ? acc[0][1] : acc[0][0];
                    float z1 = (l & 1) ? acc[1][1] : acc[1][0];
                    float z2 = (l & 1) ? acc[2][1] : acc[2][0];
                    float z3 = (l & 1) ? acc[3][1] : acc[3][0];
                    float y0 = (l & 2) ? z1 : z0;
                    float y1 = (l & 2) ? z3 : z2;
                    float kk = ((l & 4) ? y1 : y0) + rb3;
                    float ynew;
                    if (mode == 1) {
                        rk1 = kk;
                        ynew = fmaf(dt * (1.0f / 3.0f), rk1, rH);
                    } else if (mode == 2) {
                        rk2 = kk;
                        ynew = fmaf(dt, rk2 - rk1 * (1.0f / 3.0f), rH);
                    } else if (mode == 3) {
                        rk3 = kk;
                        ynew = fmaf(dt, rk1 - rk2 + rk3, rH);
                    } else {
                        rH = fmaf(dt * 0.125f, rk1 + 3.0f * (rk2 + rk3) + kk, rH);
                        ynew = rH;
                        if (ownD) traj[(((size_t)(b0 + bD) * 64 + s) * 8 + step) * 64 + jD] = rH;
                    }
                    if (ownD) sY[bD][jD] = ynew;
                }
                __syncthreads();
            }
        }
    }
    if (ownD) out[(size_t)(b0 + bD) * 64 + jD] = rH;
}

extern "C" void kernel_launch(void* const* d_in, const int* in_sizes, int n_in,
                              void* d_out, int out_size, void* d_ws, size_t ws_size,
                              hipStream_t stream) {
    const float* quat = (const float*)d_in[0];
    const float* W1   = (const float*)d_in[1];
    const float* b1   = (const float*)d_in[2];
    const float* W2   = (const float*)d_in[3];
    const float* b2   = (const float*)d_in[4];
    const float* W3   = (const float*)d_in[5];
    const float* b3   = (const float*)d_in[6];
    float* out = (float*)d_out;

    odernn_kernel<<<1024 / BT, NTHR, 0, stream>>>(quat, W1, b1, W2, b2, W3, b3, out);
}

// Round 7
// 5748.141 us; speedup vs baseline: 11.0266x; 1.3551x over previous
//
#include <hip/hip_runtime.h>
#include <math.h>

#define NTHR 512
#define BT 4

__device__ __forceinline__ float fast_tanh(float x) {
    float ax = fabsf(x);
    float e  = __expf(-2.0f * ax);                       // in (0,1], never overflows
    float r  = (1.0f - e) * __builtin_amdgcn_rcpf(1.0f + e);
    return copysignf(r, x);
}

// Packed FP32 FMA, broadcasting one half of s01 to both results via op_sel.
// pk_fma_lo: d.x += s01.x*w.x ; d.y += s01.x*w.y
__device__ __forceinline__ void pk_fma_lo(float2& d, float2 s01, float2 w) {
    asm("v_pk_fma_f32 %0, %1, %2, %0 op_sel:[0,0,0] op_sel_hi:[0,1,1]"
        : "+v"(d) : "v"(s01), "v"(w));
}
// pk_fma_hi: d.x += s01.y*w.x ; d.y += s01.y*w.y
__device__ __forceinline__ void pk_fma_hi(float2& d, float2 s01, float2 w) {
    asm("v_pk_fma_f32 %0, %1, %2, %0 op_sel:[1,0,0] op_sel_hi:[1,1,1]"
        : "+v"(d) : "v"(s01), "v"(w));
}

union F4 { float4 v; float2 p[2]; };

__global__ __launch_bounds__(NTHR, 2)
void odernn_kernel(const float* __restrict__ quat,   // [1024][64][4]
                   const float* __restrict__ W1,     // [68][256]
                   const float* __restrict__ b1,     // [256]
                   const float* __restrict__ W2,     // [256][256]
                   const float* __restrict__ b2,     // [256]
                   const float* __restrict__ W3,     // [256][64]
                   const float* __restrict__ b3,     // [64]
                   float* __restrict__ out)          // [1024*64] hfinal, then [1024][64][8][64] traj
{
    // LDS: activations + partial sums only; ALL weights live in registers.
    __shared__ __align__(16) float sRed[8192];    // 32 KB, union: L2 partials [8][4][256] / L3 partials [32][4][64]
    __shared__ __align__(16) float sH1[4][256];   // 4 KB
    __shared__ __align__(16) float sH2[4][256];   // 4 KB
    __shared__ __align__(16) float sC1[4][256];   // 4 KB
    __shared__ __align__(16) float sY[4][64];     // 1 KB

    const int t = threadIdx.x;
    const int w = t >> 6;            // wave 0..7
    const int l = t & 63;            // lane
    const int b0 = blockIdx.x * BT;

    // ---- phase mappings (all dup-free weight ownership) ----
    // A (L1): lane-pair k-split: col j1a, k-half kha
    const int j1a = t >> 1;          // 0..255
    const int kha = (t & 1) * 32;    // k base: 0 or 32
    // B (L2): wave = k-slice (32 k), lane = j-quad
    const int kb2 = w * 32;
    // C (L2 reduce): col j1c, batch pair bc
    const int j1c = t & 255;
    const int bc  = (t >> 8) * 2;
    // D (L3): u3 = j-quad, ks3 = k-slice (32 slices of 8)
    const int u3  = t & 15;
    const int ks3 = t >> 4;
    const int kb3 = ks3 * 8;
    // E (RK4, t<256): batch rb = wave (0..3), state dim rj = lane
    const int rb = (t >> 6) & 3;
    const int rj = l;

    // ---- weights -> registers (loaded once) ----
    float w1r[32];                                   // W1h[kha+k][j1a]
    #pragma unroll
    for (int k = 0; k < 32; ++k) w1r[k] = W1[(kha + k) * 256 + j1a];

    // W2[kb2+k][l*4 + jj] as j-pairs: w2p[k*2+p] = (col jj=2p, jj=2p+1)
    float2 w2p[64];
    const float2* __restrict__ W2v2 = (const float2*)W2;
    #pragma unroll
    for (int k = 0; k < 32; ++k) {
        w2p[k * 2 + 0] = W2v2[(size_t)(kb2 + k) * 128 + l * 2 + 0];
        w2p[k * 2 + 1] = W2v2[(size_t)(kb2 + k) * 128 + l * 2 + 1];
    }
    float w3r[32];                                   // W3[kb3+k][u3*4+jj]
    #pragma unroll
    for (int k = 0; k < 8; ++k) {
        float4 v = *(const float4*)&W3[(kb3 + k) * 64 + u3 * 4];
        w3r[k * 4 + 0] = v.x; w3r[k * 4 + 1] = v.y;
        w3r[k * 4 + 2] = v.z; w3r[k * 4 + 3] = v.w;
    }
    float w1q[4];                                    // q-part of W1, col j1c (used t<256)
    #pragma unroll
    for (int m = 0; m < 4; ++m) w1q[m] = W1[(64 + m) * 256 + j1c];

    const float rb1  = b1[j1c];
    const float rb2c = b2[j1c];
    const float rb3e = b3[rj];

    float rH  = (rj == 0) ? 1.0f : 0.0f;   // meaningful for t<256
    float rk1 = 0.0f, rk2 = 0.0f, rk3 = 0.0f;
    if (t < 256) sY[rb][rj] = rH;

    const float dt = 1.0f / 7.0f;
    float* __restrict__ traj = out + 1024 * 64;

    for (int s = 0; s < 64; ++s) {
        // ---- per-token: c1 = b1 + q @ W1q ; record initial state ----
        if (t < 256) {
            float4 q0 = *(const float4*)&quat[((size_t)(b0 + 0) * 64 + s) * 4];
            float4 q1 = *(const float4*)&quat[((size_t)(b0 + 1) * 64 + s) * 4];
            float4 q2 = *(const float4*)&quat[((size_t)(b0 + 2) * 64 + s) * 4];
            float4 q3 = *(const float4*)&quat[((size_t)(b0 + 3) * 64 + s) * 4];
            sC1[0][t] = fmaf(q0.x, w1q[0], fmaf(q0.y, w1q[1], fmaf(q0.z, w1q[2], fmaf(q0.w, w1q[3], rb1))));
            sC1[1][t] = fmaf(q1.x, w1q[0], fmaf(q1.y, w1q[1], fmaf(q1.z, w1q[2], fmaf(q1.w, w1q[3], rb1))));
            sC1[2][t] = fmaf(q2.x, w1q[0], fmaf(q2.y, w1q[1], fmaf(q2.z, w1q[2], fmaf(q2.w, w1q[3], rb1))));
            sC1[3][t] = fmaf(q3.x, w1q[0], fmaf(q3.y, w1q[1], fmaf(q3.z, w1q[2], fmaf(q3.w, w1q[3], rb1))));
            traj[(((size_t)(b0 + rb) * 64 + s) * 8 + 0) * 64 + rj] = rH;
        }
        __syncthreads();

        for (int step = 1; step < 8; ++step) {
            #pragma unroll
            for (int mode = 1; mode <= 4; ++mode) {
                // ---------- A: h1 = tanh(y @ W1h + c1), lane-pair k-split ----------
                {
                    float a0 = 0.0f, a1 = 0.0f, a2 = 0.0f, a3 = 0.0f;
                    const float4* y4 = (const float4*)&sY[0][0];
                    const int yb = (t & 1) * 8;      // float4 index of k-half
                    #pragma unroll
                    for (int k4 = 0; k4 < 8; ++k4) {
                        float4 y0 = y4[0 * 16 + yb + k4];
                        float4 y1 = y4[1 * 16 + yb + k4];
                        float4 y2 = y4[2 * 16 + yb + k4];
                        float4 y3 = y4[3 * 16 + yb + k4];
                        #pragma unroll
                        for (int r = 0; r < 4; ++r) {
                            float wv = w1r[k4 * 4 + r];
                            a0 = fmaf(((const float*)&y0)[r], wv, a0);
                            a1 = fmaf(((const float*)&y1)[r], wv, a1);
                            a2 = fmaf(((const float*)&y2)[r], wv, a2);
                            a3 = fmaf(((const float*)&y3)[r], wv, a3);
                        }
                    }
                    a0 += __shfl_xor(a0, 1);
                    a1 += __shfl_xor(a1, 1);
                    a2 += __shfl_xor(a2, 1);
                    a3 += __shfl_xor(a3, 1);
                    const int bw = (t & 1) * 2;
                    float vA = (t & 1) ? a2 : a0;
                    float vB = (t & 1) ? a3 : a1;
                    sH1[bw][j1a]     = fast_tanh(vA + sC1[bw][j1a]);
                    sH1[bw + 1][j1a] = fast_tanh(vB + sC1[bw + 1][j1a]);
                }
                __syncthreads();
                // ---------- B: layer-2 partials via v_pk_fma_f32 (2 FMA/inst) ----------
                {
                    float2 acc[4][2];                // [batch][j-pair]
                    #pragma unroll
                    for (int bb = 0; bb < 4; ++bb) {
                        acc[bb][0] = make_float2(0.0f, 0.0f);
                        acc[bb][1] = make_float2(0.0f, 0.0f);
                    }
                    #pragma unroll
                    for (int bp = 0; bp < 2; ++bp) {     // batch pairs: (0,1), (2,3)
                        #pragma unroll
                        for (int k4 = 0; k4 < 8; ++k4) {
                            const int k = kb2 + k4 * 4;
                            F4 ha, hb;
                            ha.v = *(const float4*)&sH1[bp * 2 + 0][k];
                            hb.v = *(const float4*)&sH1[bp * 2 + 1][k];
                            #pragma unroll
                            for (int r2 = 0; r2 < 2; ++r2) {   // k-offsets 2*r2, 2*r2+1
                                const int wlo = (k4 * 4 + 2 * r2 + 0) * 2;
                                const int whi = (k4 * 4 + 2 * r2 + 1) * 2;
                                #pragma unroll
                                for (int p = 0; p < 2; ++p) {
                                    pk_fma_lo(acc[bp * 2 + 0][p], ha.p[r2], w2p[wlo + p]);
                                    pk_fma_hi(acc[bp * 2 + 0][p], ha.p[r2], w2p[whi + p]);
                                    pk_fma_lo(acc[bp * 2 + 1][p], hb.p[r2], w2p[wlo + p]);
                                    pk_fma_hi(acc[bp * 2 + 1][p], hb.p[r2], w2p[whi + p]);
                                }
                            }
                        }
                    }
                    // partials: sRed as [8 ks][4 b][256 j]
                    #pragma unroll
                    for (int bb = 0; bb < 4; ++bb)
                        *(float4*)&sRed[w * 1024 + bb * 256 + l * 4] =
                            make_float4(acc[bb][0].x, acc[bb][0].y, acc[bb][1].x, acc[bb][1].y);
                }
                __syncthreads();
                // ---------- C: layer-2 reduce + tanh ----------
                {
                    float v0 = rb2c, v1 = 0.0f, u0 = rb2c, u1 = 0.0f;
                    #pragma unroll
                    for (int ks = 0; ks < 8; ks += 2) {
                        v0 += sRed[ks * 1024 + bc * 256 + j1c];
                        u0 += sRed[ks * 1024 + (bc + 1) * 256 + j1c];
                        v1 += sRed[(ks + 1) * 1024 + bc * 256 + j1c];
                        u1 += sRed[(ks + 1) * 1024 + (bc + 1) * 256 + j1c];
                    }
                    sH2[bc][j1c]     = fast_tanh(v0 + v1);
                    sH2[bc + 1][j1c] = fast_tanh(u0 + u1);
                }
                __syncthreads();
                // ---------- D: layer-3 partials, W3 in registers ----------
                {
                    float acc[4][4];
                    #pragma unroll
                    for (int bb = 0; bb < 4; ++bb)
                        #pragma unroll
                        for (int jj = 0; jj < 4; ++jj) acc[bb][jj] = 0.0f;
                    #pragma unroll
                    for (int k4 = 0; k4 < 2; ++k4) {
                        const int k = kb3 + k4 * 4;
                        float4 h0 = *(const float4*)&sH2[0][k];
                        float4 h1v = *(const float4*)&sH2[1][k];
                        float4 h2v = *(const float4*)&sH2[2][k];
                        float4 h3v = *(const float4*)&sH2[3][k];
                        #pragma unroll
                        for (int r = 0; r < 4; ++r) {
                            const int wi = (k4 * 4 + r) * 4;
                            float f0 = ((const float*)&h0)[r];
                            float f1 = ((const float*)&h1v)[r];
                            float f2 = ((const float*)&h2v)[r];
                            float f3 = ((const float*)&h3v)[r];
                            #pragma unroll
                            for (int jj = 0; jj < 4; ++jj) {
                                acc[0][jj] = fmaf(f0, w3r[wi + jj], acc[0][jj]);
                                acc[1][jj] = fmaf(f1, w3r[wi + jj], acc[1][jj]);
                                acc[2][jj] = fmaf(f2, w3r[wi + jj], acc[2][jj]);
                                acc[3][jj] = fmaf(f3, w3r[wi + jj], acc[3][jj]);
                            }
                        }
                    }
                    // partials: sRed as [32 ks][4 b][64 j]
                    #pragma unroll
                    for (int bb = 0; bb < 4; ++bb)
                        *(float4*)&sRed[ks3 * 256 + bb * 64 + u3 * 4] =
                            make_float4(acc[bb][0], acc[bb][1], acc[bb][2], acc[bb][3]);
                }
                __syncthreads();
                // ---------- E: layer-3 reduce + RK4 (3/8-rule) ----------
                if (t < 256) {
                    float s0 = rb3e, s1 = 0.0f, s2 = 0.0f, s3 = 0.0f;
                    #pragma unroll
                    for (int ks = 0; ks < 32; ks += 4) {
                        s0 += sRed[(ks + 0) * 256 + rb * 64 + rj];
                        s1 += sRed[(ks + 1) * 256 + rb * 64 + rj];
                        s2 += sRed[(ks + 2) * 256 + rb * 64 + rj];
                        s3 += sRed[(ks + 3) * 256 + rb * 64 + rj];
                    }
                    float k = (s0 + s1) + (s2 + s3);
                    float ynew;
                    if (mode == 1) {
                        rk1 = k;
                        ynew = fmaf(dt * (1.0f / 3.0f), rk1, rH);
                    } else if (mode == 2) {
                        rk2 = k;
                        ynew = fmaf(dt, rk2 - rk1 * (1.0f / 3.0f), rH);
                    } else if (mode == 3) {
                        rk3 = k;
                        ynew = fmaf(dt, rk1 - rk2 + rk3, rH);
                    } else {
                        rH = fmaf(dt * 0.125f, rk1 + 3.0f * (rk2 + rk3) + k, rH);
                        ynew = rH;
                        traj[(((size_t)(b0 + rb) * 64 + s) * 8 + step) * 64 + rj] = rH;
                    }
                    sY[rb][rj] = ynew;
                }
                __syncthreads();
            }
        }
    }
    if (t < 256) out[(size_t)(b0 + rb) * 64 + rj] = rH;
}

extern "C" void kernel_launch(void* const* d_in, const int* in_sizes, int n_in,
                              void* d_out, int out_size, void* d_ws, size_t ws_size,
                              hipStream_t stream) {
    const float* quat = (const float*)d_in[0];
    const float* W1   = (const float*)d_in[1];
    const float* b1   = (const float*)d_in[2];
    const float* W2   = (const float*)d_in[3];
    const float* b2   = (const float*)d_in[4];
    const float* W3   = (const float*)d_in[5];
    const float* b3   = (const float*)d_in[6];
    float* out = (float*)d_out;

    odernn_kernel<<<1024 / BT, NTHR, 0, stream>>>(quat, W1, b1, W2, b2, W3, b3, out);
}

// Round 8
// 5597.743 us; speedup vs baseline: 11.3229x; 1.0269x over previous
//
#include <hip/hip_runtime.h>
#include <math.h>

#define NTHR 512
#define BT 4

__device__ __forceinline__ float fast_tanh(float x) {
    float ax = fabsf(x);
    float e  = __expf(-2.0f * ax);                       // in (0,1], never overflows
    float r  = (1.0f - e) * __builtin_amdgcn_rcpf(1.0f + e);
    return copysignf(r, x);
}

// quad_perm DPP add: x += lanes within quad. VALU pipe, NOT the DS pipe.
// 0xB1 = [1,0,3,2] (xor 1), 0x4E = [2,3,0,1] (xor 2)
template <int CTRL>
__device__ __forceinline__ float dpp_add(float x) {
    int yi = __builtin_amdgcn_update_dpp(0, __builtin_bit_cast(int, x), CTRL, 0xF, 0xF, true);
    return x + __builtin_bit_cast(float, yi);
}

__global__ __launch_bounds__(NTHR, 2)
void odernn_kernel(const float* __restrict__ quat,   // [1024][64][4]
                   const float* __restrict__ W1,     // [68][256]
                   const float* __restrict__ b1,     // [256]
                   const float* __restrict__ W2,     // [256][256]
                   const float* __restrict__ b2,     // [256]
                   const float* __restrict__ W3,     // [256][64]
                   const float* __restrict__ b3,     // [64]
                   float* __restrict__ out)          // [1024*64] hfinal, then [1024][64][8][64] traj
{
    __shared__ __align__(16) float sRed[8192];    // 32 KB union: B partials [8][4][256] / D partials [8][4][64]
    __shared__ __align__(16) float sH1[4][256];   // 4 KB
    __shared__ __align__(16) float sH2[4][256];   // 4 KB
    __shared__ __align__(16) float sC1[4][256];   // 4 KB
    __shared__ __align__(16) float sY[4][64];     // 1 KB

    const int t = threadIdx.x;
    const int w = t >> 6;            // wave 0..7
    const int l = t & 63;            // lane
    const int q = l & 3;             // quad lane id (batch owner after DPP reduce)
    const int b0 = blockIdx.x * BT;

    // ---- A (L1): thread owns (j-pair j0..j0+1, 4 batches, k-quarter) ----
    const int ksa = l & 3;                    // k-quarter 0..3 (16 k each)
    const int j0  = (w * 16 + (l >> 2)) * 2;  // j-pair base, 0..254
    // ---- B (L2): wave = k-slice of 32, lane = j-quad (round-3 form) ----
    const int kb2 = w * 32;
    // ---- C: col j1c, batch pair bc ----
    const int j1c = t & 255;
    const int bc  = (t >> 8) * 2;
    // ---- D (L3): k-slice 0..31 = (wave, lane&3); j-quad = l>>2 ----
    const int ksd = (w << 2) | q;
    const int kb3 = ksd * 8;
    const int u3  = l >> 2;          // j-quad 0..15
    const int j03 = u3 * 4;
    // ---- E (RK4, t<256): batch rb = wave, state dim rj = lane ----
    const int rb = (t >> 6) & 3;
    const int rj = l;

    // ---- weights -> registers (dup-free) ----
    float w1r[32];                                   // W1h[ksa*16+k][j0+jj]
    #pragma unroll
    for (int k = 0; k < 16; ++k) {
        float2 v = *(const float2*)&W1[(ksa * 16 + k) * 256 + j0];
        w1r[k * 2 + 0] = v.x; w1r[k * 2 + 1] = v.y;
    }
    float w2r[128];                                  // W2[kb2+k][l*4+jj]
    const float4* __restrict__ W2v4 = (const float4*)W2;
    #pragma unroll
    for (int k = 0; k < 32; ++k) {
        float4 v = W2v4[(size_t)(kb2 + k) * 64 + l];
        w2r[k * 4 + 0] = v.x; w2r[k * 4 + 1] = v.y;
        w2r[k * 4 + 2] = v.z; w2r[k * 4 + 3] = v.w;
    }
    float w3r[32];                                   // W3[kb3+k][j03+jj]
    #pragma unroll
    for (int k = 0; k < 8; ++k) {
        float4 v = *(const float4*)&W3[(kb3 + k) * 64 + j03];
        w3r[k * 4 + 0] = v.x; w3r[k * 4 + 1] = v.y;
        w3r[k * 4 + 2] = v.z; w3r[k * 4 + 3] = v.w;
    }
    float w1q[4];                                    // q-part of W1, col j1c (t<256 producer)
    #pragma unroll
    for (int m = 0; m < 4; ++m) w1q[m] = W1[(64 + m) * 256 + j1c];

    const float rb1  = b1[j1c];
    const float rb2c = b2[j1c];
    const float rb3e = b3[rj];

    float rH  = (rj == 0) ? 1.0f : 0.0f;   // meaningful for t<256
    float rk1 = 0.0f, rk2 = 0.0f, rk3 = 0.0f;
    if (t < 256) sY[rb][rj] = rH;

    const float dt = 1.0f / 7.0f;
    float* __restrict__ traj = out + 1024 * 64;

    for (int s = 0; s < 64; ++s) {
        // ---- per-token: c1 = b1 + quat @ W1q ; record initial state ----
        if (t < 256) {
            float4 q0 = *(const float4*)&quat[((size_t)(b0 + 0) * 64 + s) * 4];
            float4 q1 = *(const float4*)&quat[((size_t)(b0 + 1) * 64 + s) * 4];
            float4 q2 = *(const float4*)&quat[((size_t)(b0 + 2) * 64 + s) * 4];
            float4 q3 = *(const float4*)&quat[((size_t)(b0 + 3) * 64 + s) * 4];
            sC1[0][t] = fmaf(q0.x, w1q[0], fmaf(q0.y, w1q[1], fmaf(q0.z, w1q[2], fmaf(q0.w, w1q[3], rb1))));
            sC1[1][t] = fmaf(q1.x, w1q[0], fmaf(q1.y, w1q[1], fmaf(q1.z, w1q[2], fmaf(q1.w, w1q[3], rb1))));
            sC1[2][t] = fmaf(q2.x, w1q[0], fmaf(q2.y, w1q[1], fmaf(q2.z, w1q[2], fmaf(q2.w, w1q[3], rb1))));
            sC1[3][t] = fmaf(q3.x, w1q[0], fmaf(q3.y, w1q[1], fmaf(q3.z, w1q[2], fmaf(q3.w, w1q[3], rb1))));
            traj[(((size_t)(b0 + rb) * 64 + s) * 8 + 0) * 64 + rj] = rH;
        }
        __syncthreads();

        for (int step = 1; step < 8; ++step) {
            #pragma unroll
            for (int mode = 1; mode <= 4; ++mode) {
                // ---------- A: h1 = tanh(y @ W1h + c1); k-split 4 via quad-DPP ----------
                {
                    float a[4][2];
                    #pragma unroll
                    for (int bb = 0; bb < 4; ++bb) { a[bb][0] = 0.0f; a[bb][1] = 0.0f; }
                    const float4* y4 = (const float4*)&sY[0][0];
                    #pragma unroll
                    for (int kk = 0; kk < 4; ++kk) {
                        float4 yv0 = y4[0 * 16 + ksa * 4 + kk];
                        float4 yv1 = y4[1 * 16 + ksa * 4 + kk];
                        float4 yv2 = y4[2 * 16 + ksa * 4 + kk];
                        float4 yv3 = y4[3 * 16 + ksa * 4 + kk];
                        #pragma unroll
                        for (int r = 0; r < 4; ++r) {
                            float w0 = w1r[(kk * 4 + r) * 2 + 0];
                            float w1v = w1r[(kk * 4 + r) * 2 + 1];
                            float f0 = ((const float*)&yv0)[r];
                            float f1 = ((const float*)&yv1)[r];
                            float f2 = ((const float*)&yv2)[r];
                            float f3 = ((const float*)&yv3)[r];
                            a[0][0] = fmaf(f0, w0, a[0][0]); a[0][1] = fmaf(f0, w1v, a[0][1]);
                            a[1][0] = fmaf(f1, w0, a[1][0]); a[1][1] = fmaf(f1, w1v, a[1][1]);
                            a[2][0] = fmaf(f2, w0, a[2][0]); a[2][1] = fmaf(f2, w1v, a[2][1]);
                            a[3][0] = fmaf(f3, w0, a[3][0]); a[3][1] = fmaf(f3, w1v, a[3][1]);
                        }
                    }
                    // quad reduce (VALU DPP), then quad-lane q owns batch q
                    #pragma unroll
                    for (int bb = 0; bb < 4; ++bb) {
                        #pragma unroll
                        for (int jj = 0; jj < 2; ++jj) {
                            a[bb][jj] = dpp_add<0xB1>(a[bb][jj]);
                            a[bb][jj] = dpp_add<0x4E>(a[bb][jj]);
                        }
                    }
                    float z0 = (l & 1) ? a[1][0] : a[0][0];
                    float z1 = (l & 1) ? a[3][0] : a[2][0];
                    float o0 = (l & 2) ? z1 : z0;
                    z0 = (l & 1) ? a[1][1] : a[0][1];
                    z1 = (l & 1) ? a[3][1] : a[2][1];
                    float o1 = (l & 2) ? z1 : z0;
                    float2 c = *(const float2*)&sC1[q][j0];
                    float2 h = make_float2(fast_tanh(o0 + c.x), fast_tanh(o1 + c.y));
                    *(float2*)&sH1[q][j0] = h;
                }
                __syncthreads();
                // ---------- B: layer-2 partials (round-3 form, W2 in registers) ----------
                {
                    float acc[4][4];
                    #pragma unroll
                    for (int bb = 0; bb < 4; ++bb)
                        #pragma unroll
                        for (int jj = 0; jj < 4; ++jj) acc[bb][jj] = 0.0f;
                    #pragma unroll
                    for (int k4 = 0; k4 < 8; ++k4) {
                        const int k = kb2 + k4 * 4;
                        float4 h0 = *(const float4*)&sH1[0][k];
                        float4 h1v = *(const float4*)&sH1[1][k];
                        float4 h2v = *(const float4*)&sH1[2][k];
                        float4 h3v = *(const float4*)&sH1[3][k];
                        #pragma unroll
                        for (int r = 0; r < 4; ++r) {
                            const int wi = (k4 * 4 + r) * 4;
                            float f0 = ((const float*)&h0)[r];
                            float f1 = ((const float*)&h1v)[r];
                            float f2 = ((const float*)&h2v)[r];
                            float f3 = ((const float*)&h3v)[r];
                            #pragma unroll
                            for (int jj = 0; jj < 4; ++jj) {
                                acc[0][jj] = fmaf(f0, w2r[wi + jj], acc[0][jj]);
                                acc[1][jj] = fmaf(f1, w2r[wi + jj], acc[1][jj]);
                                acc[2][jj] = fmaf(f2, w2r[wi + jj], acc[2][jj]);
                                acc[3][jj] = fmaf(f3, w2r[wi + jj], acc[3][jj]);
                            }
                        }
                    }
                    #pragma unroll
                    for (int bb = 0; bb < 4; ++bb)
                        *(float4*)&sRed[w * 1024 + bb * 256 + l * 4] =
                            make_float4(acc[bb][0], acc[bb][1], acc[bb][2], acc[bb][3]);
                }
                __syncthreads();
                // ---------- C: layer-2 reduce + tanh ----------
                {
                    float v0 = rb2c, v1 = 0.0f, u0 = rb2c, u1 = 0.0f;
                    #pragma unroll
                    for (int ks = 0; ks < 8; ks += 2) {
                        v0 += sRed[ks * 1024 + bc * 256 + j1c];
                        u0 += sRed[ks * 1024 + (bc + 1) * 256 + j1c];
                        v1 += sRed[(ks + 1) * 1024 + bc * 256 + j1c];
                        u1 += sRed[(ks + 1) * 1024 + (bc + 1) * 256 + j1c];
                    }
                    sH2[bc][j1c]     = fast_tanh(v0 + v1);
                    sH2[bc + 1][j1c] = fast_tanh(u0 + u1);
                }
                __syncthreads();
                // ---------- D: layer-3 partials; quad-DPP collapses k-split 32 -> 8 ----------
                {
                    float acc[4][4];
                    #pragma unroll
                    for (int bb = 0; bb < 4; ++bb)
                        #pragma unroll
                        for (int jj = 0; jj < 4; ++jj) acc[bb][jj] = 0.0f;
                    #pragma unroll
                    for (int kk = 0; kk < 2; ++kk) {
                        const int k = kb3 + kk * 4;
                        float4 h0 = *(const float4*)&sH2[0][k];
                        float4 h1v = *(const float4*)&sH2[1][k];
                        float4 h2v = *(const float4*)&sH2[2][k];
                        float4 h3v = *(const float4*)&sH2[3][k];
                        #pragma unroll
                        for (int r = 0; r < 4; ++r) {
                            const int wi = (kk * 4 + r) * 4;
                            float f0 = ((const float*)&h0)[r];
                            float f1 = ((const float*)&h1v)[r];
                            float f2 = ((const float*)&h2v)[r];
                            float f3 = ((const float*)&h3v)[r];
                            #pragma unroll
                            for (int jj = 0; jj < 4; ++jj) {
                                acc[0][jj] = fmaf(f0, w3r[wi + jj], acc[0][jj]);
                                acc[1][jj] = fmaf(f1, w3r[wi + jj], acc[1][jj]);
                                acc[2][jj] = fmaf(f2, w3r[wi + jj], acc[2][jj]);
                                acc[3][jj] = fmaf(f3, w3r[wi + jj], acc[3][jj]);
                            }
                        }
                    }
                    #pragma unroll
                    for (int bb = 0; bb < 4; ++bb)
                        #pragma unroll
                        for (int jj = 0; jj < 4; ++jj) {
                            acc[bb][jj] = dpp_add<0xB1>(acc[bb][jj]);
                            acc[bb][jj] = dpp_add<0x4E>(acc[bb][jj]);
                        }
                    // quad-lane q keeps batch q, all 4 j; XOR-swizzled b128 store
                    float o0, o1, o2, o3;
                    {
                        float z0 = (l & 1) ? acc[1][0] : acc[0][0];
                        float z1 = (l & 1) ? acc[3][0] : acc[2][0];
                        o0 = (l & 2) ? z1 : z0;
                        z0 = (l & 1) ? acc[1][1] : acc[0][1];
                        z1 = (l & 1) ? acc[3][1] : acc[2][1];
                        o1 = (l & 2) ? z1 : z0;
                        z0 = (l & 1) ? acc[1][2] : acc[0][2];
                        z1 = (l & 1) ? acc[3][2] : acc[2][2];
                        o2 = (l & 2) ? z1 : z0;
                        z0 = (l & 1) ? acc[1][3] : acc[0][3];
                        z1 = (l & 1) ? acc[3][3] : acc[2][3];
                        o3 = (l & 2) ? z1 : z0;
                    }
                    // sRed as [8 w][4 b][64 j], j-quad slot XOR'd by batch
                    ((float4*)sRed)[w * 64 + q * 16 + (u3 ^ q)] = make_float4(o0, o1, o2, o3);
                }
                __syncthreads();
                // ---------- E: 8-way reduce + RK4 (3/8-rule) ----------
                if (t < 256) {
                    const int jb = rb * 64 + (((rj >> 2) ^ rb) * 4) + (rj & 3);
                    float s0 = rb3e, s1 = 0.0f, s2 = 0.0f, s3 = 0.0f;
                    #pragma unroll
                    for (int wk = 0; wk < 8; wk += 4) {
                        s0 += sRed[(wk + 0) * 256 + jb];
                        s1 += sRed[(wk + 1) * 256 + jb];
                        s2 += sRed[(wk + 2) * 256 + jb];
                        s3 += sRed[(wk + 3) * 256 + jb];
                    }
                    float k = (s0 + s1) + (s2 + s3);
                    float ynew;
                    if (mode == 1) {
                        rk1 = k;
                        ynew = fmaf(dt * (1.0f / 3.0f), rk1, rH);
                    } else if (mode == 2) {
                        rk2 = k;
                        ynew = fmaf(dt, rk2 - rk1 * (1.0f / 3.0f), rH);
                    } else if (mode == 3) {
                        rk3 = k;
                        ynew = fmaf(dt, rk1 - rk2 + rk3, rH);
                    } else {
                        rH = fmaf(dt * 0.125f, rk1 + 3.0f * (rk2 + rk3) + k, rH);
                        ynew = rH;
                        traj[(((size_t)(b0 + rb) * 64 + s) * 8 + step) * 64 + rj] = rH;
                    }
                    sY[rb][rj] = ynew;
                }
                __syncthreads();
            }
        }
    }
    if (t < 256) out[(size_t)(b0 + rb) * 64 + rj] = rH;
}

extern "C" void kernel_launch(void* const* d_in, const int* in_sizes, int n_in,
                              void* d_out, int out_size, void* d_ws, size_t ws_size,
                              hipStream_t stream) {
    const float* quat = (const float*)d_in[0];
    const float* W1   = (const float*)d_in[1];
    const float* b1   = (const float*)d_in[2];
    const float* W2   = (const float*)d_in[3];
    const float* b2   = (const float*)d_in[4];
    const float* W3   = (const float*)d_in[5];
    const float* b3   = (const float*)d_in[6];
    float* out = (float*)d_out;

    odernn_kernel<<<1024 / BT, NTHR, 0, stream>>>(quat, W1, b1, W2, b2, W3, b3, out);
}